// Round 11
// baseline (248.878 us; speedup 1.0000x reference)
//
#include <hip/hip_runtime.h>
#include <math.h>

static constexpr int F     = 64;
static constexpr int GRIDV = 64;
static constexpr int SEG   = 16 * GRIDV * GRIDV;   // 65536 clusters
static constexpr int MINB  = 256;                  // blocks for k_min
// edge pipeline
static constexpr int GPART = 512;                  // blocks for edge hist/partition
static constexpr int PTHR  = 512;                  // threads for edge hist/partition
static constexpr int NBIN  = 512;                  // coarse bins (top 9 bits)
static constexpr int BSH   = 23;                   // key >> 23 -> coarse bin
static constexpr int ETBL  = NBIN * GPART;         // 262144
static constexpr int SCAP  = 10240;                // subsort LDS staging cap (+27 sigma)
// node pipeline
static constexpr int NGP   = 512;                  // blocks for node partition
static constexpr int NTH   = 256;                  // threads for node partition
static constexpr int NTBL  = NBIN * NGP;           // 262144
static constexpr int JTBL  = NTBL + ETBL;          // 524288 joint-scanned entries

typedef float __attribute__((ext_vector_type(4))) f32x4;

__device__ __forceinline__ float wave_min(float v) {
    for (int o = 32; o > 0; o >>= 1) v = fminf(v, __shfl_down(v, o));
    return v;
}
__device__ __forceinline__ float wave_max(float v) {
    for (int o = 32; o > 0; o >>= 1) v = fmaxf(v, __shfl_down(v, o));
    return v;
}
__device__ __forceinline__ f32x4 vmax4(f32x4 a, f32x4 b) {
    f32x4 r;
    r.x = fmaxf(a.x, b.x); r.y = fmaxf(a.y, b.y);
    r.z = fmaxf(a.z, b.z); r.w = fmaxf(a.w, b.w);
    return r;
}

// Block-wide inclusive scan, shfl-based (2 barriers). EXEC-mask safe.
template <int NT>
__device__ __forceinline__ unsigned block_incl_scan(unsigned v, int t) {
    __shared__ unsigned wsum[NT / 64];
    int lane = t & 63, w = t >> 6;
    unsigned sc = v;
    #pragma unroll
    for (int o = 1; o < 64; o <<= 1) {
        unsigned u = __shfl_up(sc, o);
        if (lane >= o) sc += u;
    }
    if (lane == 63) wsum[w] = sc;
    __syncthreads();
    if (w == 0 && lane < NT / 64) {
        unsigned ws = wsum[lane];
        #pragma unroll
        for (int o = 1; o < NT / 64; o <<= 1) {
            unsigned u = __shfl_up(ws, o);
            if (lane >= o) ws += u;
        }
        wsum[lane] = ws;
    }
    __syncthreads();
    return sc + ((w > 0) ? wsum[w - 1] : 0u);
}

// ---- hdr init (capture-safe; no memset) ----
__global__ void k_hdrinit(unsigned* hdr) {
    hdr[0] = 0x7F800000u;   // +inf
    hdr[1] = 0x7F800000u;
}

// ---- global min of pos; positions >= 0 so int-punned atomicMin is exact ----
__global__ void k_min(const float2* __restrict__ pos, int n, unsigned* hdr) {
    __shared__ float shx[4], shy[4];
    int stride = gridDim.x * blockDim.x;
    float mx = INFINITY, my = INFINITY;
    for (int i = blockIdx.x * blockDim.x + threadIdx.x; i < n; i += stride) {
        float2 p = pos[i];
        mx = fminf(mx, p.x); my = fminf(my, p.y);
    }
    mx = wave_min(mx); my = wave_min(my);
    int w = threadIdx.x >> 6;
    if ((threadIdx.x & 63) == 0) { shx[w] = mx; shy[w] = my; }
    __syncthreads();
    if (threadIdx.x == 0) {
        mx = fminf(fminf(shx[0], shx[1]), fminf(shx[2], shx[3]));
        my = fminf(fminf(shy[0], shy[1]), fminf(shy[2], shy[3]));
        atomicMin((int*)&hdr[0], __float_as_int(mx));
        atomicMin((int*)&hdr[1], __float_as_int(my));
    }
}

// ---- cluster ids + coarse 512-bin per-block table ----
__global__ __launch_bounds__(NTH) void k_cluster(const float2* __restrict__ pos,
                          const int* __restrict__ batch, int n,
                          const unsigned* __restrict__ hdr, int* __restrict__ cl,
                          unsigned* __restrict__ ntable) {
    __shared__ unsigned hist[NBIN];
    int t = threadIdx.x, b = blockIdx.x;
    for (int j = t; j < NBIN; j += NTH) hist[j] = 0u;
    __syncthreads();
    float sx = __int_as_float((int)hdr[0]);
    float sy = __int_as_float((int)hdr[1]);
    for (int i = b * NTH + t; i < n; i += NGP * NTH) {
        float2 p = pos[i];
        int vx = min(max((int)floorf((p.x - sx) * 64.0f), 0), GRIDV - 1);
        int vy = min(max((int)floorf((p.y - sy) * 64.0f), 0), GRIDV - 1);
        int c = batch[i] * (GRIDV * GRIDV) + vy * GRIDV + vx;
        cl[i] = c;
        atomicAdd(&hist[(unsigned)c >> 7], 1u);
    }
    __syncthreads();
    for (int j = t; j < NBIN; j += NTH) ntable[j * NGP + b] = hist[j];
}

// ---- edge keys + coarse histogram (written at table[NTBL + ...]) ----
__global__ __launch_bounds__(PTHR) void k_ehist(const int* __restrict__ ei, int e,
                        const int* __restrict__ cl,
                        unsigned* __restrict__ keysA, unsigned* __restrict__ etbl) {
    __shared__ unsigned hist[NBIN];
    int t = threadIdx.x, b = blockIdx.x;
    for (int j = t; j < NBIN; j += PTHR) hist[j] = 0u;
    __syncthreads();
    for (int i = b * PTHR + t; i < e; i += GPART * PTHR) {
        unsigned r = (unsigned)cl[ei[i]];
        unsigned c = (unsigned)cl[ei[e + i]];
        unsigned k = (r << 16) | c;
        keysA[i] = k;
        atomicAdd(&hist[k >> BSH], 1u);
    }
    __syncthreads();
    for (int j = t; j < NBIN; j += PTHR) etbl[j * GPART + b] = hist[j];
}

// ---- joint exclusive scan over both tables: stage 1 ----
__global__ void k_scan1(const unsigned* __restrict__ cnt, unsigned* __restrict__ off,
                        unsigned* __restrict__ blksum) {
    int t = threadIdx.x;
    int g = blockIdx.x * 1024 + t;
    unsigned v = cnt[g];
    unsigned incl = block_incl_scan<1024>(v, t);
    off[g] = incl - v;
    if (t == 1023) blksum[blockIdx.x] = incl;
}

// stage 2: add block bases; up to 512 stage-1 blocks
__global__ void k_scan_add(unsigned* __restrict__ off, const unsigned* __restrict__ blksum,
                           int nblk, int nent, unsigned total) {
    __shared__ unsigned sh[512];
    int t = threadIdx.x, b = blockIdx.x;
    if (t < 512) sh[t] = (t < b && t < nblk) ? blksum[t] : 0u;
    __syncthreads();
    for (int s = 256; s > 0; s >>= 1) {
        if (t < s) sh[t] += sh[t + s];
        __syncthreads();
    }
    off[b * 1024 + t] += sh[0];
    if (b == 0 && t == 0) off[nent] = total;
}

// ---- node coarse partition; per-block counts from scanned-table diffs ----
__global__ __launch_bounds__(NTH) void k_npart(const int* __restrict__ cl,
                       const float2* __restrict__ pos, int n,
                       const unsigned* __restrict__ ntable,
                       unsigned* __restrict__ pc, unsigned* __restrict__ pn,
                       float2* __restrict__ ppos) {
    __shared__ unsigned stage_c[2048], stage_n[2048];
    __shared__ float stage_px[2048], stage_py[2048];
    __shared__ unsigned h[NBIN], cur[NBIN], tbl_s[NBIN];
    int t = threadIdx.x, b = blockIdx.x;
    for (int j = t; j < NBIN; j += NTH) {
        unsigned a = ntable[j * NGP + b];       // boundary ntable[NTBL] = n (joint scan)
        tbl_s[j] = a;
        h[j] = ntable[j * NGP + b + 1] - a;
    }
    __syncthreads();
    unsigned a0 = h[2 * t], a1 = h[2 * t + 1];
    unsigned incl = block_incl_scan<NTH>(a0 + a1, t);
    unsigned base = incl - (a0 + a1);
    cur[2 * t] = base;
    cur[2 * t + 1] = base + a0;
    __syncthreads();
    for (int i = b * NTH + t; i < n; i += NGP * NTH) {
        unsigned c = (unsigned)cl[i];
        float2 p = pos[i];
        unsigned q = atomicAdd(&cur[c >> 7], 1u);
        stage_c[q] = c; stage_n[q] = (unsigned)i;
        stage_px[q] = p.x; stage_py[q] = p.y;
    }
    __syncthreads();
    int cnt = (int)cur[NBIN - 1];
    for (int j = t; j < cnt; j += NTH) {
        unsigned c = stage_c[j];
        unsigned bin = c >> 7;
        unsigned start = cur[bin] - h[bin];
        unsigned g = tbl_s[bin] + ((unsigned)j - start);
        pc[g] = c; pn[g] = stage_n[j];
        ppos[g] = make_float2(stage_px[j], stage_py[j]);
    }
}

// ---- per coarse bin: node_off, pos means, grouped node order ----
__global__ __launch_bounds__(256) void k_ngroup(const unsigned* __restrict__ pc,
                         const unsigned* __restrict__ pn, const float2* __restrict__ ppos,
                         const unsigned* __restrict__ ntable, int n,
                         unsigned* __restrict__ node_off, int* __restrict__ node_sorted,
                         float2* __restrict__ out_pos) {
    __shared__ unsigned cnt[128], sc[128], cur[128];
    __shared__ float psx[128], psy[128];
    int b = blockIdx.x, t = threadIdx.x;
    if (t < 128) { cnt[t] = 0u; psx[t] = 0.f; psy[t] = 0.f; }
    __syncthreads();
    int beg = (int)ntable[b * NGP];
    int end = (int)ntable[(b + 1) * NGP];      // b==NBIN-1 -> ntable[NTBL] == n
    for (int i = beg + t; i < end; i += 256) {
        unsigned c = pc[i] & 127u;
        float2 p = ppos[i];
        atomicAdd(&cnt[c], 1u);
        atomicAdd(&psx[c], p.x);
        atomicAdd(&psy[c], p.y);
    }
    __syncthreads();
    if (t < 128) sc[t] = cnt[t];
    __syncthreads();
    for (int s = 1; s < 128; s <<= 1) {
        unsigned u = (t >= s && t < 128) ? sc[t - s] : 0u;
        __syncthreads();
        if (t < 128) sc[t] += u;
        __syncthreads();
    }
    if (t < 128) {
        unsigned basec = (unsigned)beg + sc[t] - cnt[t];
        node_off[b * 128 + t] = basec;
        cur[t] = basec;
        unsigned c2 = cnt[t];
        out_pos[b * 128 + t] = c2 ? make_float2(psx[t] / (float)c2, psy[t] / (float)c2)
                                  : make_float2(0.f, 0.f);
    }
    if (b == NBIN - 1 && t == 0) node_off[SEG] = (unsigned)n;
    __syncthreads();
    for (int i = beg + t; i < end; i += 256) {
        unsigned c = pc[i] & 127u;
        unsigned slot = atomicAdd(&cur[c], 1u);
        node_sorted[slot] = (int)pn[i];
    }
}

// ---- feature max: wave-coalesced node-id load + shfl broadcast ----
// Row loop: WAVE-UNIFORM trip count with CLAMPED row indices (idempotent for
// max). Divergent trips would make __shfl read EXEC=0 lanes -> 0 on CDNA.
__global__ __launch_bounds__(256) void k_pool(const float* __restrict__ x,
                      const int* __restrict__ node_sorted, const unsigned* __restrict__ off,
                      float* __restrict__ out_x) {
    int wid  = threadIdx.x >> 6;
    int lane = threadIdx.x & 63;
    int s = blockIdx.x * 4 + wid;
    unsigned beg = off[s], end = off[s + 1];
    int g   = lane >> 4;            // row offset 0..3
    int cl4 = (lane & 15) << 2;     // column base
    f32x4 m0, m1, m2, m3;
    m0.x = m0.y = m0.z = m0.w = -INFINITY;
    m1 = m0; m2 = m0; m3 = m0;
    for (unsigned base = beg; base < end; base += 64) {
        int m = (int)min(64u, end - base);
        int nd_my = (lane < m) ? node_sorted[base + lane] : 0;
        int last = m - 1;
        int K = (m + 15) >> 4;                    // uniform across the wave
        for (int k = 0; k < K; ++k) {
            int j = g + (k << 4);
            int j0 = min(j, last);
            int j1 = min(j + 4, last);
            int j2 = min(j + 8, last);
            int j3 = min(j + 12, last);
            int n0 = __shfl(nd_my, j0);
            int n1 = __shfl(nd_my, j1);
            int n2 = __shfl(nd_my, j2);
            int n3 = __shfl(nd_my, j3);
            f32x4 v0 = __builtin_nontemporal_load((const f32x4*)&x[(size_t)n0 * F + cl4]);
            f32x4 v1 = __builtin_nontemporal_load((const f32x4*)&x[(size_t)n1 * F + cl4]);
            f32x4 v2 = __builtin_nontemporal_load((const f32x4*)&x[(size_t)n2 * F + cl4]);
            f32x4 v3 = __builtin_nontemporal_load((const f32x4*)&x[(size_t)n3 * F + cl4]);
            m0 = vmax4(m0, v0);
            m1 = vmax4(m1, v1);
            m2 = vmax4(m2, v2);
            m3 = vmax4(m3, v3);
        }
    }
    m0 = vmax4(vmax4(m0, m1), vmax4(m2, m3));
    #pragma unroll
    for (int o = 16; o <= 32; o <<= 1) {
        m0.x = fmaxf(m0.x, __shfl_xor(m0.x, o));
        m0.y = fmaxf(m0.y, __shfl_xor(m0.y, o));
        m0.z = fmaxf(m0.z, __shfl_xor(m0.z, o));
        m0.w = fmaxf(m0.w, __shfl_xor(m0.w, o));
    }
    if (g == 0) {
        f32x4 r;
        if (end > beg) r = m0;
        else { r.x = r.y = r.z = r.w = 0.f; }
        *(f32x4*)&out_x[(size_t)s * F + cl4] = r;
    }
}

// ---- coalesced coarse partition (A -> B); counts from scanned diffs, bias=n ----
__global__ __launch_bounds__(PTHR) void k_partition(const unsigned* __restrict__ keysA, int e,
                            const unsigned* __restrict__ etbl, unsigned bias,
                            unsigned* __restrict__ keysB) {
    __shared__ unsigned stage[8192];
    __shared__ unsigned h[NBIN], cur[NBIN], tbl_s[NBIN];
    int t = threadIdx.x, b = blockIdx.x;
    unsigned a = etbl[t * GPART + b] - bias;       // boundary etbl[ETBL] = n+e
    unsigned hv = (etbl[t * GPART + b + 1] - bias) - a;
    tbl_s[t] = a;
    h[t] = hv;
    __syncthreads();
    unsigned incl = block_incl_scan<PTHR>(hv, t);
    cur[t] = incl - hv;
    __syncthreads();
    for (int i = b * PTHR + t; i < e; i += GPART * PTHR) {
        unsigned k = keysA[i];
        unsigned p = atomicAdd(&cur[k >> BSH], 1u);
        stage[p] = k;
    }
    __syncthreads();
    int cnt = (int)cur[NBIN - 1];
    for (int j = t; j < cnt; j += PTHR) {
        unsigned k = stage[j];
        unsigned bin = k >> BSH;
        unsigned start = cur[bin] - h[bin];
        keysB[tbl_s[bin] + ((unsigned)j - start)] = k;
    }
}

// ---- 13-bit LDS counting sort per bin + run-finish; writes SORTED KEYS + pmax ----
__global__ __launch_bounds__(512) void k_subsort(const unsigned* __restrict__ src,
                         unsigned* __restrict__ dst, const unsigned* __restrict__ etbl,
                         unsigned bias, const float2* __restrict__ pos_pool,
                         float* __restrict__ pmax) {
    __shared__ unsigned hist[8192];     // slot(d) = (d&15)*512 + (d>>4)
    __shared__ unsigned stage[SCAP];
    __shared__ float shm[8];
    int b = blockIdx.x, t = threadIdx.x;
    int beg = (int)(etbl[b * GPART] - bias);
    int end = (int)(etbl[(b + 1) * GPART] - bias);   // b==NBIN-1 -> e
    int len = end - beg;
    if (len <= 0) { if (t == 0) pmax[b] = 0.f; return; }
    for (int j = t; j < 8192; j += 512) hist[j] = 0u;
    __syncthreads();
    for (int i = beg + t; i < end; i += 512) {
        unsigned d = (src[i] >> 10) & 8191u;
        atomicAdd(&hist[((d & 15u) << 9) | (d >> 4)], 1u);
    }
    __syncthreads();
    unsigned loc[16];
    unsigned s = 0;
    #pragma unroll
    for (int u = 0; u < 16; ++u) { loc[u] = s; s += hist[u * 512 + t]; }
    unsigned incl = block_incl_scan<512>(s, t);
    bool inlds = (len <= SCAP);
    unsigned base0 = (inlds ? 0u : (unsigned)beg) + incl - s;
    #pragma unroll
    for (int u = 0; u < 16; ++u) hist[u * 512 + t] = base0 + loc[u];
    __syncthreads();
    float am = 0.f;
    if (inlds) {
        for (int i = beg + t; i < end; i += 512) {
            unsigned k = src[i];
            unsigned d = (k >> 10) & 8191u;
            stage[atomicAdd(&hist[((d & 15u) << 9) | (d >> 4)], 1u)] = k;
        }
        __syncthreads();
        // run-finish: runs = equal top-22 bits (never cross bins)
        for (int j = t; j < len; j += 512) {
            unsigned hi = stage[j] >> 10;
            if (j > 0 && (stage[j - 1] >> 10) == hi) continue;
            int rend = j + 1;
            while (rend < len && (stage[rend] >> 10) == hi) ++rend;
            for (int a2 = j + 1; a2 < rend; ++a2) {
                unsigned v = stage[a2]; int c = a2 - 1;
                while (c >= j && stage[c] > v) { stage[c + 1] = stage[c]; --c; }
                stage[c + 1] = v;
            }
        }
        __syncthreads();
        for (int j = t; j < len; j += 512) {
            unsigned k = stage[j];
            dst[beg + j] = k;
            bool first = (j == 0) || (stage[j - 1] != k);
            unsigned r = k >> 16, c = k & 0xFFFFu;
            if (first && r != c) {
                float2 pr = pos_pool[r], pcc = pos_pool[c];
                am = fmaxf(am, fmaxf(fabsf(pr.x - pcc.x), fabsf(pr.y - pcc.y)));
            }
        }
    } else {
        // 27-sigma-unreachable fallback in global
        for (int i = beg + t; i < end; i += 512) {
            unsigned k = src[i];
            unsigned d = (k >> 10) & 8191u;
            dst[atomicAdd(&hist[((d & 15u) << 9) | (d >> 4)], 1u)] = k;
        }
        __threadfence();
        __syncthreads();
        for (int j = beg + t; j < end; j += 512) {
            unsigned hi = dst[j] >> 10;
            if (j > beg && (dst[j - 1] >> 10) == hi) continue;
            int rend = j + 1;
            while (rend < end && (dst[rend] >> 10) == hi) ++rend;
            for (int a2 = j + 1; a2 < rend; ++a2) {
                unsigned v = dst[a2]; int c = a2 - 1;
                while (c >= j && dst[c] > v) { dst[c + 1] = dst[c]; --c; }
                dst[c + 1] = v;
            }
        }
        __threadfence();
        __syncthreads();
        for (int j = beg + t; j < end; j += 512) {
            unsigned k = dst[j];
            bool first = (j == beg) || (dst[j - 1] != k);
            unsigned r = k >> 16, c = k & 0xFFFFu;
            if (first && r != c) {
                float2 pr = pos_pool[r], pcc = pos_pool[c];
                am = fmaxf(am, fmaxf(fabsf(pr.x - pcc.x), fabsf(pr.y - pcc.y)));
            }
        }
    }
    am = wave_max(am);
    if ((t & 63) == 0) shm[t >> 6] = am;
    __syncthreads();
    if (t == 0) {
        float m = shm[0];
        #pragma unroll
        for (int i2 = 1; i2 < 8; ++i2) m = fmaxf(m, shm[i2]);
        pmax[b] = m;
    }
}

// ---- final outputs from sorted keys (single coalesced pass) ----
__global__ __launch_bounds__(256) void k_eout(const unsigned* __restrict__ keys, int e,
                         const float2* __restrict__ pos_pool, const float* __restrict__ pmax,
                         float* __restrict__ out_erow, float* __restrict__ out_ecol,
                         float* __restrict__ out_valid, float2* __restrict__ out_attr) {
    __shared__ float shm[4];
    int t = threadIdx.x;
    float m = fmaxf(pmax[t], pmax[t + 256]);
    m = wave_max(m);
    if ((t & 63) == 0) shm[t >> 6] = m;
    __syncthreads();
    float denom = 2.0f * fmaxf(fmaxf(shm[0], shm[1]), fmaxf(shm[2], shm[3]));
    int i = blockIdx.x * blockDim.x + t;
    if (i >= e) return;
    unsigned k = keys[i];
    bool first = (i == 0) || (keys[i - 1] != k);
    unsigned r = k >> 16, c = k & 0xFFFFu;
    bool valid = first && (r != c);
    float ax = 0.f, ay = 0.f;
    if (valid) {
        float2 pr = pos_pool[r], pcc = pos_pool[c];
        ax = (pr.x - pcc.x) / denom + 0.5f;
        ay = (pr.y - pcc.y) / denom + 0.5f;
    }
    out_erow[i]  = valid ? (float)r : 0.f;
    out_ecol[i]  = valid ? (float)c : 0.f;
    out_valid[i] = valid ? 1.f : 0.f;
    out_attr[i]  = make_float2(ax, ay);
}

extern "C" void kernel_launch(void* const* d_in, const int* in_sizes, int n_in,
                              void* d_out, int out_size, void* d_ws, size_t ws_size,
                              hipStream_t stream) {
    const float* x    = (const float*)d_in[0];
    const float* pos  = (const float*)d_in[1];
    const int* batch  = (const int*)d_in[2];
    const int* ei     = (const int*)d_in[3];
    const int n = in_sizes[2];
    const int e = in_sizes[3] / 2;

    float* out      = (float*)d_out;
    float* out_x    = out;                                   // [SEG, F]
    float* out_pos  = out_x  + (size_t)SEG * F;              // [SEG, 2]
    float* out_erow = out_pos + (size_t)SEG * 2;             // [E]
    float* out_ecol = out_erow + e;                          // [E]
    float* out_attr = out_ecol + e;                          // [E, 2]
    float* out_val  = out_attr + (size_t)2 * e;              // [E]

    const int nb_e = (e + 255) / 256;

    // Workspace layout — NO ALIASING between any two live ranges.
    char* w = (char*)d_ws;
    unsigned* hdr         = (unsigned*)w;                            // 2 u32 (pad 256)
    int*      cl          = (int*)(w + 256);                         // [n]
    int*      node_sorted = (int*)(w + 256 + (size_t)n * 4);         // [n]
    unsigned* node_off    = (unsigned*)(w + 256 + (size_t)n * 8);    // [SEG+1]
    unsigned* table       = node_off + SEG + 1;                      // [JTBL+1]
    unsigned* keysA       = table + JTBL + 1;                        // [e]
    unsigned* keysB       = keysA + e;                               // [e]
    unsigned* pc          = keysB + e;                               // [n]
    unsigned* pn          = pc + n;                                  // [n]
    float2*   ppos        = (float2*)(pn + n);                       // [n]
    unsigned* blksum      = (unsigned*)(ppos + n);                   // [512]
    float*    pmax        = (float*)(blksum + 512);                  // [NBIN]
    unsigned* ntable      = table;                                   // [NTBL]
    unsigned* etbl        = table + NTBL;                            // [ETBL] (+1 via JTBL+1)

    k_hdrinit<<<1, 1, 0, stream>>>(hdr);
    k_min<<<MINB, 256, 0, stream>>>((const float2*)pos, n, hdr);
    k_cluster<<<NGP, NTH, 0, stream>>>((const float2*)pos, batch, n, hdr, cl, ntable);
    k_ehist<<<GPART, PTHR, 0, stream>>>(ei, e, cl, keysA, etbl);
    // joint scan of ntable (NTBL) + etable (ETBL); etable entries carry +n bias
    k_scan1<<<JTBL / 1024, 1024, 0, stream>>>(table, table, blksum);
    k_scan_add<<<JTBL / 1024, 1024, 0, stream>>>(table, blksum, JTBL / 1024, JTBL,
                                                 (unsigned)(n + e));
    k_npart<<<NGP, NTH, 0, stream>>>(cl, (const float2*)pos, n, ntable, pc, pn, ppos);
    k_ngroup<<<NBIN, 256, 0, stream>>>(pc, pn, ppos, ntable, n, node_off, node_sorted,
                                       (float2*)out_pos);
    k_partition<<<GPART, PTHR, 0, stream>>>(keysA, e, etbl, (unsigned)n, keysB);
    k_subsort<<<NBIN, 512, 0, stream>>>(keysB, keysA, etbl, (unsigned)n,
                                        (const float2*)out_pos, pmax);
    k_pool<<<SEG / 4, 256, 0, stream>>>(x, node_sorted, node_off, out_x);
    k_eout<<<nb_e, 256, 0, stream>>>(keysA, e, (const float2*)out_pos, pmax,
                                     out_erow, out_ecol, out_val, (float2*)out_attr);
}